// Round 5
// baseline (202.932 us; speedup 1.0000x reference)
//
#include <hip/hip_runtime.h>
#include <stdint.h>
#include <stddef.h>

typedef int v4i  __attribute__((ext_vector_type(4)));
typedef int v16i __attribute__((ext_vector_type(16)));

#define GLOAD16(gp, lp) __builtin_amdgcn_global_load_lds( \
    (const __attribute__((address_space(1))) void*)(gp),  \
    (__attribute__((address_space(3))) void*)(lp), 16, 0, 0)

#define PH_BAR()     __builtin_amdgcn_s_barrier()
#define WAIT_LGKM0() asm volatile("s_waitcnt lgkmcnt(0)" ::: "memory")
#define WAIT_VM(n)   asm volatile("s_waitcnt vmcnt(" #n ")" ::: "memory")
#define SCHED_FENCE() __builtin_amdgcn_sched_barrier(0)
#define PRIO1() __builtin_amdgcn_s_setprio(1)
#define PRIO0() __builtin_amdgcn_s_setprio(0)

static __device__ __forceinline__ int pack4(int a, int b, int c, int d) {
    return (a & 255) | ((b & 255) << 8) | ((c & 255) << 16) | (d << 24);
}

// ---------------- pack: int32 (values in [-128,127]) -> int8, both arrays ----------------
__global__ __launch_bounds__(256) void pack2_kernel(const int* __restrict__ srcA, v4i* __restrict__ dstA, int nA,
                                                    const int* __restrict__ srcB, v4i* __restrict__ dstB, int nB) {
    int i = blockIdx.x * blockDim.x + threadIdx.x;
    const int* src; v4i* dst;
    if (i < nA) { src = srcA; dst = dstA; }
    else { i -= nA; if (i >= nB) return; src = srcB; dst = dstB; }
    const v4i* s = reinterpret_cast<const v4i*>(src) + (size_t)i * 4;
    v4i v0 = s[0], v1 = s[1], v2 = s[2], v3 = s[3];
    v4i r;
    r.x = pack4(v0.x, v0.y, v0.z, v0.w);
    r.y = pack4(v1.x, v1.y, v1.z, v1.w);
    r.z = pack4(v2.x, v2.y, v2.z, v2.w);
    r.w = pack4(v3.x, v3.y, v3.z, v3.w);
    dst[i] = r;
}

// ============ 256x256 8-phase i8 GEMM, 32x32x32 MFMA ============
// A[Nrows][K] i8 packed, B[Ncols][K] i8 packed (W rows = out cols), int32 epilogue out.
// 8 waves = 2(M) x 4(N); per-wave out 128x64; K-tile = 128 bytes; 2 K-tiles/iter.
// LDS: A 2buf x [256][128] @0 (64KB), B same @65536. st-swizzle chunk16 ^= (row&7).
// Quadrant = (mh half: 2 x 32-row frags) x (n-pair: 1 x 32-col frag) x 4 k-slices(32B)
// = 8 x mfma_i32_32x32x32_i8. Read counts/phase and stage/vmcnt queues identical to
// the 16x16x64 version (8/4/8/4 b128; vmcnt(6)@P3/P7-end, vmcnt(4)@P4/P8-end).
__global__ __launch_bounds__(512, 2) void gemm_q8_8ph(
    const char* __restrict__ Apk, const char* __restrict__ Bpk,
    const int* __restrict__ bias, const float* __restrict__ wscale,
    const float* __restrict__ is_p, const float* __restrict__ os_p,
    const int* __restrict__ zp_p,
    int* __restrict__ out, int K, int Ncols)
{
    __shared__ char lds[131072];

    const int tid  = threadIdx.x;
    const int wid  = tid >> 6;
    const int lane = tid & 63;
    const int l7 = lane & 7, l3 = lane >> 3;
    const int l31 = lane & 31, hi5 = lane >> 5;

    // bijective XCD-aware swizzle (m204)
    int swz;
    {
        const int nwg = gridDim.x;
        const int q = nwg >> 3, r = nwg & 7;
        const int xcd = blockIdx.x & 7;
        const int base = (xcd < r) ? xcd * (q + 1) : r * (q + 1) + (xcd - r) * q;
        swz = base + (blockIdx.x >> 3);
    }
    const int nbc  = Ncols >> 8;
    const int brow = swz / nbc, bcol = swz % nbc;

    const int wr = wid >> 2, wc = wid & 3;

    // staging: wave wid covers rows wid*8+l3 (+64 per 2nd load, +128*h); source pre-swizzled
    const char* Ab = Apk + (size_t)(brow * 256 + wid * 8 + l3) * K + ((l7 ^ l3) << 4);
    const char* Bb = Bpk + (size_t)(bcol * 256 + wid * 8 + l3) * K + ((l7 ^ l3) << 4);

    // 32x32 fragment reads: lane row/col = l31; k-bytes = s*32 + hi5*16, chunk ^= row&7.
    // col(s) = ((2s+hi5) ^ l7) << 4  (loop-invariant; col(s) = col(0) ^ (s<<5))
    int colw[4];
#pragma unroll
    for (int s = 0; s < 4; ++s) colw[s] = (((s << 1) + hi5) ^ l7) << 4;
    int aOff[2][2];
#pragma unroll
    for (int mh = 0; mh < 2; ++mh)
#pragma unroll
        for (int m = 0; m < 2; ++m)
            aOff[mh][m] = ((wr << 7) + (mh << 6) + (m << 5) + l31) << 7;
    int bOff[2];
#pragma unroll
    for (int nj = 0; nj < 2; ++nj)
        bOff[nj] = ((wc << 6) + (nj << 5) + l31) << 7;

    v16i acc[4][2];
#pragma unroll
    for (int m = 0; m < 4; ++m)
#pragma unroll
        for (int n = 0; n < 2; ++n)
#pragma unroll
            for (int j = 0; j < 16; ++j)
                acc[m][n][j] = 0;

    v4i af[2][4], bf[4], bf2[4];

    auto stage = [&](const char* gb, int ldsOp, int bufo, int h, int t) {
        const char* g = gb + (size_t)(h * 128) * K + ((size_t)t << 7);
        char* l = lds + (ldsOp + bufo + (h << 14) + (wid << 10));
        GLOAD16(g, l);
        GLOAD16(g + (size_t)64 * K, l + 8192);
    };
    auto ldA = [&](int bufo, int mh) {
#pragma unroll
        for (int m = 0; m < 2; ++m)
#pragma unroll
            for (int s = 0; s < 4; ++s)
                af[m][s] = *(const v4i*)(lds + bufo + aOff[mh][m] + colw[s]);
    };
    auto ldB = [&](v4i (&bx)[4], int bufo, int nj) {
#pragma unroll
        for (int s = 0; s < 4; ++s)
            bx[s] = *(const v4i*)(lds + 65536 + bufo + bOff[nj] + colw[s]);
    };

#define MFMA_Q(mh, bfx, nIdx) do {                                                \
    _Pragma("unroll") for (int m_ = 0; m_ < 2; ++m_)                              \
    _Pragma("unroll") for (int s_ = 0; s_ < 4; ++s_)                              \
        acc[((mh) << 1) + m_][nIdx] = __builtin_amdgcn_mfma_i32_32x32x32_i8(      \
            af[m_][s_], bfx[s_], acc[((mh) << 1) + m_][nIdx], 0, 0, 0);           \
} while (0)

    // ---- prologue: tile0 A+B (8 loads) + tile1 B (4 loads); preload bf(even n0) ----
    stage(Ab, 0,     0,     0, 0);  stage(Ab, 0,     0,     1, 0);
    stage(Bb, 65536, 0,     0, 0);  stage(Bb, 65536, 0,     1, 0);
    stage(Bb, 65536, 32768, 0, 1);  stage(Bb, 65536, 32768, 1, 1);
    WAIT_VM(4);           // tile0 A+B landed; tile1 B (4) outstanding
    PH_BAR();
    ldB(bf, 0, 0);        // even-tile n0 (lgkm covered by P1's wait)

    const int niter = K >> 8;   // 2 K-tiles (256 B of K) per iteration
    for (int i = 0; i < niter - 1; ++i) {
        SCHED_FENCE();
        const int tO1 = 2 * i + 1, tE = 2 * i + 2, tO = 2 * i + 3;

        // P1: even mh0 x n0   [8 reads]
        ldA(0, 0);
        stage(Ab, 0, 32768, 0, tO1);
        PH_BAR(); WAIT_LGKM0();
        PRIO1(); MFMA_Q(0, bf, 0); PRIO0();
        PH_BAR();
        // P2: even mh0 x n1   [4 reads]
        ldB(bf2, 0, 1);
        stage(Ab, 0, 32768, 1, tO1);
        PH_BAR(); WAIT_LGKM0();
        PRIO1(); MFMA_Q(0, bf2, 1); PRIO0();
        PH_BAR();
        // P3: even mh1 x n0   [8 reads]; vmcnt(6) drains odd-B before P4's read-ahead
        ldA(0, 1);
        stage(Bb, 65536, 0, 0, tE);
        PH_BAR(); WAIT_LGKM0();
        PRIO1(); MFMA_Q(1, bf, 0); PRIO0();
        WAIT_VM(6);
        PH_BAR();
        // P4: even mh1 x n1   [4 reads: odd-tile n0 read-ahead]
        ldB(bf, 32768, 0);
        stage(Bb, 65536, 0, 1, tE);
        PH_BAR();
        PRIO1(); MFMA_Q(1, bf2, 1); PRIO0();
        WAIT_VM(4);
        PH_BAR();
        SCHED_FENCE();
        // P5: odd mh0 x n0    [8 reads]
        ldA(32768, 0);
        stage(Ab, 0, 0, 0, tE);
        PH_BAR(); WAIT_LGKM0();
        PRIO1(); MFMA_Q(0, bf, 0); PRIO0();
        PH_BAR();
        // P6: odd mh0 x n1    [4 reads]
        ldB(bf2, 32768, 1);
        stage(Ab, 0, 0, 1, tE);
        PH_BAR(); WAIT_LGKM0();
        PRIO1(); MFMA_Q(0, bf2, 1); PRIO0();
        PH_BAR();
        // P7: odd mh1 x n0    [8 reads]; vmcnt(6) drains next-even-B before P8's read-ahead
        ldA(32768, 1);
        stage(Bb, 65536, 32768, 0, tO);
        PH_BAR(); WAIT_LGKM0();
        PRIO1(); MFMA_Q(1, bf, 0); PRIO0();
        WAIT_VM(6);
        PH_BAR();
        // P8: odd mh1 x n1    [4 reads: next-even n0 read-ahead]
        ldB(bf, 0, 0);
        stage(Bb, 65536, 32768, 1, tO);
        PH_BAR();
        PRIO1(); MFMA_Q(1, bf2, 1); PRIO0();
        WAIT_VM(4);
        PH_BAR();
    }

    // ---- peeled last iteration: stage only its own odd-A; single vmcnt(0) ----
    {
        SCHED_FENCE();
        const int tL = 2 * niter - 1;
        // L1
        ldA(0, 0);
        stage(Ab, 0, 32768, 0, tL);
        PH_BAR(); WAIT_LGKM0();
        PRIO1(); MFMA_Q(0, bf, 0); PRIO0();
        PH_BAR();
        // L2
        ldB(bf2, 0, 1);
        stage(Ab, 0, 32768, 1, tL);
        PH_BAR(); WAIT_LGKM0();
        PRIO1(); MFMA_Q(0, bf2, 1); PRIO0();
        PH_BAR();
        // L3 ; drain everything (odd-B from prev P7/P8 + odd-A from L1/L2)
        ldA(0, 1);
        PH_BAR(); WAIT_LGKM0();
        PRIO1(); MFMA_Q(1, bf, 0); PRIO0();
        WAIT_VM(0);
        PH_BAR();
        // L4
        ldB(bf, 32768, 0);
        PH_BAR();
        PRIO1(); MFMA_Q(1, bf2, 1); PRIO0();
        PH_BAR();
        // L5
        ldA(32768, 0);
        PH_BAR(); WAIT_LGKM0();
        PRIO1(); MFMA_Q(0, bf, 0); PRIO0();
        PH_BAR();
        // L6
        ldB(bf2, 32768, 1);
        PH_BAR(); WAIT_LGKM0();
        PRIO1(); MFMA_Q(0, bf2, 1); PRIO0();
        PH_BAR();
        // L7
        ldA(32768, 1);
        PH_BAR(); WAIT_LGKM0();
        PRIO1(); MFMA_Q(1, bf, 0); PRIO0();
        PH_BAR();
        // L8
        PRIO1(); MFMA_Q(1, bf2, 1); PRIO0();
    }
#undef MFMA_Q

    // ---------------- epilogue: 32x32 C layout, row-major store order ----------------
    // C/D: col = l31, row = (reg&3) + 8*(reg>>2) + 4*hi5  [m101, dtype-independent]
    const float is = *is_p, os = *os_p;
    const float zp = (float)(*zp_p);
    const int colb = (bcol << 8) + (wc << 6) + l31;
    float sc[2]; int bv[2];
#pragma unroll
    for (int nj = 0; nj < 2; ++nj) {
        sc[nj] = is * wscale[colb + (nj << 5)] / os;
        bv[nj] = bias[colb + (nj << 5)];
    }
#pragma unroll
    for (int mf = 0; mf < 4; ++mf) {
        const int rowbase = (brow << 8) + (wr << 7) + (mf << 5) + (hi5 << 2);
#pragma unroll
        for (int rg = 0; rg < 4; ++rg) {
#pragma unroll
            for (int j = 0; j < 4; ++j) {
                const int row = rowbase + (rg << 3) + j;
                int* op = out + (size_t)row * Ncols + colb;
#pragma unroll
                for (int nj = 0; nj < 2; ++nj) {
                    float f = (float)(acc[mf][nj][(rg << 2) + j] + bv[nj]) * sc[nj] + zp;
                    f = rintf(f);
                    f = fminf(fmaxf(f, -128.f), 127.f);
                    op[nj << 5] = (int)f;
                }
            }
        }
    }
}

// ---------------- fallback 128^2 2-barrier kernel (known-correct) ----------------
template <bool PACKED>
__global__ __launch_bounds__(256) void gemm_q8(
    const void* __restrict__ Ain, const void* __restrict__ Bin,
    const int* __restrict__ bias, const float* __restrict__ wscale,
    const float* __restrict__ is_p, const float* __restrict__ os_p,
    const int* __restrict__ zp_p,
    int* __restrict__ out, int Nrows, int K, int Ncols)
{
    __shared__ char Al[128 * 64];
    __shared__ char Bl[128 * 64];

    const int tid  = threadIdx.x;
    const int wid  = tid >> 6;
    const int lane = tid & 63;

    const int nbc = Ncols / 128;
    int swz = blockIdx.x;
    if ((gridDim.x & 7) == 0) {
        const int cpx = gridDim.x >> 3;
        swz = (blockIdx.x & 7) * cpx + (blockIdx.x >> 3);
    }
    const int brow = swz / nbc;
    const int bcol = swz % nbc;
    const int wr = wid >> 1, wc = wid & 1;

    v4i acc[4][4];
#pragma unroll
    for (int m = 0; m < 4; ++m)
#pragma unroll
        for (int n = 0; n < 4; ++n)
            acc[m][n] = (v4i){0, 0, 0, 0};

    const char* Ag = nullptr;
    const char* Bg = nullptr;
    if (PACKED) {
        Ag = (const char*)Ain + (size_t)(brow * 128 + wid * 32 + (lane >> 2)) * K + (lane & 3) * 16;
        Bg = (const char*)Bin + (size_t)(bcol * 128 + wid * 32 + (lane >> 2)) * K + (lane & 3) * 16;
    }
    char* aldst = Al + wid * 2048;
    char* bldst = Bl + wid * 2048;

    const int lo16 = lane & 15, hi = lane >> 4;
    const int aoff0 = (wr * 64 + lo16) * 64 + hi * 16;
    const int boff0 = (wc * 64 + lo16) * 64 + hi * 16;

    for (int k0 = 0; k0 < K; k0 += 64) {
        if (PACKED) {
            GLOAD16(Ag + k0,          aldst);
            GLOAD16(Ag + 16 * K + k0, aldst + 1024);
            GLOAD16(Bg + k0,          bldst);
            GLOAD16(Bg + 16 * K + k0, bldst + 1024);
        } else {
            const int row = tid >> 1, half = tid & 1;
            const int* sA = (const int*)Ain + (size_t)(brow * 128 + row) * K + k0 + half * 32;
            const int* sB = (const int*)Bin + (size_t)(bcol * 128 + row) * K + k0 + half * 32;
            int pa[8], pb[8];
#pragma unroll
            for (int j = 0; j < 8; ++j) {
                v4i va = reinterpret_cast<const v4i*>(sA)[j];
                v4i vb = reinterpret_cast<const v4i*>(sB)[j];
                pa[j] = pack4(va.x, va.y, va.z, va.w);
                pb[j] = pack4(vb.x, vb.y, vb.z, vb.w);
            }
            v4i* da = (v4i*)&Al[row * 64 + half * 32];
            da[0] = (v4i){pa[0], pa[1], pa[2], pa[3]};
            da[1] = (v4i){pa[4], pa[5], pa[6], pa[7]};
            v4i* db = (v4i*)&Bl[row * 64 + half * 32];
            db[0] = (v4i){pb[0], pb[1], pb[2], pb[3]};
            db[1] = (v4i){pb[4], pb[5], pb[6], pb[7]};
        }
        __syncthreads();

        v4i afr[4], bfr[4];
#pragma unroll
        for (int m = 0; m < 4; ++m)
            afr[m] = *(const v4i*)&Al[aoff0 + m * 16 * 64];
#pragma unroll
        for (int n = 0; n < 4; ++n)
            bfr[n] = *(const v4i*)&Bl[boff0 + n * 16 * 64];
#pragma unroll
        for (int m = 0; m < 4; ++m)
#pragma unroll
            for (int n = 0; n < 4; ++n)
                acc[m][n] = __builtin_amdgcn_mfma_i32_16x16x64_i8(afr[m], bfr[n], acc[m][n], 0, 0, 0);

        __syncthreads();
    }

    const float is = *is_p;
    const float os = *os_p;
    const float zp = (float)(*zp_p);
#pragma unroll
    for (int n = 0; n < 4; ++n) {
        const int col = bcol * 128 + wc * 64 + n * 16 + lo16;
        const float sc = is * wscale[col] / os;
        const int   bv = bias[col];
#pragma unroll
        for (int m = 0; m < 4; ++m) {
            const int row0 = brow * 128 + wr * 64 + m * 16 + hi * 4;
#pragma unroll
            for (int j = 0; j < 4; ++j) {
                float f = (float)(acc[m][n][j] + bv) * sc + zp;
                f = rintf(f);
                f = fminf(fmaxf(f, -128.f), 127.f);
                out[(size_t)(row0 + j) * Ncols + col] = (int)f;
            }
        }
    }
}

extern "C" void kernel_launch(void* const* d_in, const int* in_sizes, int n_in,
                              void* d_out, int out_size, void* d_ws, size_t ws_size,
                              hipStream_t stream) {
    const int*   x32    = (const int*)d_in[0];
    const int*   w32    = (const int*)d_in[1];
    const int*   bias   = (const int*)d_in[2];
    const float* wscale = (const float*)d_in[3];
    const float* isp    = (const float*)d_in[4];
    const float* osp    = (const float*)d_in[5];
    const int*   zpp    = (const int*)d_in[6];
    int* out = (int*)d_out;

    const int OUT = in_sizes[2];            // 4096
    const int K   = in_sizes[1] / OUT;      // 4096
    const int Nr  = in_sizes[0] / K;        // 8192

    const size_t need = (size_t)Nr * K + (size_t)OUT * K;

    if (ws_size >= need) {
        char* xpk = (char*)d_ws;
        char* wpk = xpk + (size_t)Nr * K;
        const int nx16 = (Nr * K) / 16;
        const int nw16 = (OUT * K) / 16;
        pack2_kernel<<<(nx16 + nw16 + 255) / 256, 256, 0, stream>>>(
            x32, (v4i*)xpk, nx16, w32, (v4i*)wpk, nw16);
        if ((Nr & 255) == 0 && (OUT & 255) == 0 && (K & 511) == 0) {
            const int grid8 = (Nr / 256) * (OUT / 256);
            gemm_q8_8ph<<<grid8, 512, 0, stream>>>(xpk, wpk, bias, wscale, isp, osp, zpp,
                                                   out, K, OUT);
        } else {
            const int grid = (Nr / 128) * (OUT / 128);
            gemm_q8<true><<<grid, 256, 0, stream>>>(xpk, wpk, bias, wscale, isp, osp, zpp,
                                                    out, Nr, K, OUT);
        }
    } else {
        const int grid = (Nr / 128) * (OUT / 128);
        gemm_q8<false><<<grid, 256, 0, stream>>>(x32, w32, bias, wscale, isp, osp, zpp,
                                                 out, Nr, K, OUT);
    }
}